// Round 1
// baseline (1314.024 us; speedup 1.0000x reference)
//
#include <hip/hip_runtime.h>

#define BATCH   4096
#define NRULES  512
#define NNEUR   128

// Kernel 1: head[b][n] = dot(x[n][b][:], head_w[n][:]) + head_b[n]
// One wave (64 lanes) handles 4 consecutive rows rid = n*BATCH + b.
// Per row: lane i loads float4 at r=i*4 and r=256+i*4 (two fully-coalesced
// 1 KB wave transactions), FMAs against the matching head_w fragment,
// then a 6-step butterfly reduction. 4 rows/wave gives 8 independent
// float4 loads in flight per lane for latency hiding.
__global__ __launch_bounds__(256) void head_kernel(
    const float* __restrict__ x,
    const float* __restrict__ head_w,
    const float* __restrict__ head_b,
    float* __restrict__ head_out)   // [BATCH][NNEUR]
{
    const int lane = threadIdx.x & 63;
    const int wave = threadIdx.x >> 6;
    const long long wave_g = (long long)blockIdx.x * 4 + wave;
    const long long rid0 = wave_g * 4;            // first of 4 rows
    const int n  = (int)(rid0 >> 12);             // rid / BATCH
    const int b0 = (int)(rid0 & (BATCH - 1));     // rid % BATCH (all 4 share n)

    // head_w fragment for this lane (reused for all 4 rows; L2-resident)
    const float4* w4 = (const float4*)(head_w + (size_t)n * NRULES);
    const float4 wA = w4[lane];        // r in [lane*4, lane*4+4)
    const float4 wB = w4[64 + lane];   // r in [256+lane*4, ...)

    const float* xrow = x + rid0 * NRULES;
    float acc[4];
#pragma unroll
    for (int j = 0; j < 4; ++j) {
        const float4* xr = (const float4*)(xrow + (size_t)j * NRULES);
        float4 a = xr[lane];
        float4 b = xr[64 + lane];
        acc[j] = a.x * wA.x + a.y * wA.y + a.z * wA.z + a.w * wA.w
               + b.x * wB.x + b.y * wB.y + b.z * wB.z + b.w * wB.w;
    }

#pragma unroll
    for (int j = 0; j < 4; ++j) {
#pragma unroll
        for (int off = 32; off > 0; off >>= 1)
            acc[j] += __shfl_xor(acc[j], off, 64);
    }

    if (lane < 4) {
        float v = (lane == 0) ? acc[0]
                : (lane == 1) ? acc[1]
                : (lane == 2) ? acc[2]
                              : acc[3];
        v += head_b[n];
        head_out[(size_t)(b0 + lane) * NNEUR + n] = v;
    }
}

// Kernel 2: logits[b][c] = dot(head[b][:], foot_w[c][:]) + foot_b[c];
// out[b][:] = softmax(logits[b][:]). One wave per b; lane i covers
// n = 2i, 2i+1 via float2 loads; two butterfly reductions; softmax of 2.
__global__ __launch_bounds__(256) void foot_kernel(
    const float* __restrict__ head,    // [BATCH][NNEUR]
    const float* __restrict__ foot_w,  // [2][NNEUR]
    const float* __restrict__ foot_b,  // [2]
    float* __restrict__ out)           // [BATCH][2]
{
    const int lane = threadIdx.x & 63;
    const int wave = threadIdx.x >> 6;
    const int b = blockIdx.x * 4 + wave;

    const float2* h2 = (const float2*)(head + (size_t)b * NNEUR);
    const float2 h  = h2[lane];
    const float2 a0 = ((const float2*)foot_w)[lane];
    const float2 a1 = ((const float2*)(foot_w + NNEUR))[lane];

    float l0 = h.x * a0.x + h.y * a0.y;
    float l1 = h.x * a1.x + h.y * a1.y;
#pragma unroll
    for (int off = 32; off > 0; off >>= 1) {
        l0 += __shfl_xor(l0, off, 64);
        l1 += __shfl_xor(l1, off, 64);
    }

    if (lane == 0) {
        l0 += foot_b[0];
        l1 += foot_b[1];
        const float m  = fmaxf(l0, l1);
        const float e0 = __expf(l0 - m);
        const float e1 = __expf(l1 - m);
        const float inv = 1.0f / (e0 + e1);
        out[2 * b]     = e0 * inv;
        out[2 * b + 1] = e1 * inv;
    }
}

extern "C" void kernel_launch(void* const* d_in, const int* in_sizes, int n_in,
                              void* d_out, int out_size, void* d_ws, size_t ws_size,
                              hipStream_t stream) {
    const float* x      = (const float*)d_in[0];
    const float* head_w = (const float*)d_in[1];
    const float* head_b = (const float*)d_in[2];
    const float* foot_w = (const float*)d_in[3];
    const float* foot_b = (const float*)d_in[4];
    float* out  = (float*)d_out;
    float* head = (float*)d_ws;   // BATCH*NNEUR*4 = 2 MiB scratch

    // kernel 1: NNEUR*BATCH = 524288 rows, 4 rows/wave, 4 waves/block
    const int rows_per_block = 16;
    const int grid1 = (NNEUR * BATCH) / rows_per_block;   // 32768
    head_kernel<<<grid1, 256, 0, stream>>>(x, head_w, head_b, head);

    // kernel 2: one wave per batch row, 4 waves/block
    foot_kernel<<<BATCH / 4, 256, 0, stream>>>(head, foot_w, foot_b, out);
}